// Round 7
// baseline (265.207 us; speedup 1.0000x reference)
//
#include <hip/hip_runtime.h>
#include <hip/hip_bf16.h>
#include <cstdint>

#define B_  8192
#define I_  1024
#define H_  1024
#define R_  16
#define K_  2048   // I_ + H_
#define N_  4096   // 4 * H_

typedef __attribute__((ext_vector_type(4))) float f32x4;
typedef __attribute__((ext_vector_type(8))) __bf16 bf16x8;
typedef __attribute__((ext_vector_type(8))) unsigned short u16x8;
typedef unsigned short u16;

__device__ __forceinline__ u16 f2bf(float f) {
  union { float f; unsigned u; } v; v.f = f;
  unsigned u = v.u;
  return (u16)((u + 0x7fffu + ((u >> 16) & 1u)) >> 16);  // RNE
}

__device__ __forceinline__ float sigmoidf_(float x) {
  return 1.0f / (1.0f + __expf(-x));
}
__device__ __forceinline__ float tanhf_(float x) {
  return 1.0f - 2.0f / (__expf(2.0f * x) + 1.0f);  // inf-safe both tails
}

// ---------------- pack [x | h0] -> bf16 Xc[B][K] ----------------
__global__ __launch_bounds__(256) void prep_x(const float* __restrict__ x,
                                              const float* __restrict__ h0,
                                              u16* __restrict__ Xc) {
  int idx = blockIdx.x * 256 + threadIdx.x;
  int e = idx << 3;
  int b = e >> 11;
  int k = e & (K_ - 1);
  const float* src = (k < I_) ? (x + ((size_t)b << 10) + k)
                              : (h0 + ((size_t)b << 10) + (k - I_));
  const f32x4 v0 = *(const f32x4*)src;
  const f32x4 v1 = *(const f32x4*)(src + 4);
  u16x8 o;
  o[0] = f2bf(v0[0]); o[1] = f2bf(v0[1]); o[2] = f2bf(v0[2]); o[3] = f2bf(v0[3]);
  o[4] = f2bf(v1[0]); o[5] = f2bf(v1[1]); o[6] = f2bf(v1[2]); o[7] = f2bf(v1[3]);
  *(u16x8*)(Xc + (size_t)e) = o;
}

// ------- fold LoRA into weights, cast bf16, gate-interleaved rows n=h*4+g -------
__global__ __launch_bounds__(256) void prep_w(
    const float* __restrict__ W_i, const float* __restrict__ W_h,
    const float* __restrict__ b_i, const float* __restrict__ b_h,
    const float* __restrict__ A_i, const float* __restrict__ Bi,
    const float* __restrict__ A_h, const float* __restrict__ Bh,
    u16* __restrict__ Wc, float* __restrict__ bc) {
  const int gh = blockIdx.x;            // 4096 blocks = (g,h)
  const int g = gh >> 10, h = gh & (H_ - 1);
  const int tid = threadIdx.x;
  float bi[R_], bh[R_];
#pragma unroll
  for (int r = 0; r < R_; ++r) {
    bi[r] = Bi[((size_t)(g * H_ + h) << 4) + r];
    bh[r] = Bh[((size_t)(g * H_ + h) << 4) + r];
  }
  u16* dst = Wc + (size_t)(h * 4 + g) * K_;
  const float* wi = W_i + ((size_t)(g * H_ + h) << 10);
  const float* wh = W_h + ((size_t)(g * H_ + h) << 10);
#pragma unroll
  for (int it = 0; it < 4; ++it) {
    int k = it * 256 + tid;
    float acc = wi[k];
#pragma unroll
    for (int r = 0; r < R_; ++r) acc += bi[r] * A_i[((size_t)(g * R_ + r) << 10) + k];
    dst[k] = f2bf(acc);
  }
#pragma unroll
  for (int it = 0; it < 4; ++it) {
    int k = it * 256 + tid;
    float acc = wh[k];
#pragma unroll
    for (int r = 0; r < R_; ++r) acc += bh[r] * A_h[((size_t)(g * R_ + r) << 10) + k];
    dst[I_ + k] = f2bf(acc);
  }
  if (tid == 0) bc[h * 4 + g] = b_i[g * H_ + h] + b_h[g * H_ + h];
}

// -- 128x128 GEMM, 2 blocks/CU; per-half-slot dbuf + vmcnt(6)/K-tile + fused LSTM --
#define BM 128
#define BN 128
#define BK 64
#define NT (K_ / BK)   // 32 K-tiles

#define GLOAD_LDS16(gp, lp)                                                        \
  __builtin_amdgcn_global_load_lds(                                                \
      (const __attribute__((address_space(1))) void*)(gp),                         \
      (__attribute__((address_space(3))) void*)(lp), 16, 0, 0)

#define BAR()                                                                      \
  do { asm volatile("" ::: "memory"); __builtin_amdgcn_s_barrier();                \
       asm volatile("" ::: "memory"); } while (0)

#define BARL()                                                                     \
  do { asm volatile("s_waitcnt lgkmcnt(0)" ::: "memory");                          \
       __builtin_amdgcn_s_barrier(); asm volatile("" ::: "memory"); } while (0)

#define WAITV0() asm volatile("s_waitcnt vmcnt(0)" ::: "memory")
#define WAITV6() asm volatile("s_waitcnt vmcnt(6)" ::: "memory")

// 8 KB half-tile regions: A halves at 0..32KB, B halves at 32..64KB.
#define AH(HI, SL) ((u16*)(lds_raw + ((HI) * 2 + (SL)) * 8192))
#define BH(HI, SL) ((u16*)(lds_raw + 32768 + ((HI) * 2 + (SL)) * 8192))

// stage one half-tile (64 rows x 64 cols bf16 = 8KB): 2x16B/thread (256 thr).
// LDS dest linear; T2 swizzle via XOR-permuted global source chunk (rule #21).
#define STAGE_H(GBASE, HALF, K0N, REGION)                                          \
  _Pragma("unroll")                                                                \
  for (int r_ = 0; r_ < 2; ++r_) {                                                 \
    int chunk_ = r_ * 256 + tid;                                                   \
    int rl_ = chunk_ >> 3, cp_ = chunk_ & 7;                                       \
    int cc_ = cp_ ^ (rl_ & 7);                                                     \
    GLOAD_LDS16((GBASE) + (size_t)((HALF) * 64 + rl_) * K_ + (K0N) + cc_ * 8,      \
                (char*)(REGION) + chunk_ * 16);                                    \
  }

// wave (2M x 2N): wm2=(wave>>1)*32, wn2=(wave&1)*32. Each wave reads 2 frags
// from EACH half (rows mh*64 + wm2 + mi*16), so every phase involves all waves.
#define READ_A(REGION)                                                             \
  _Pragma("unroll")                                                                \
  for (int mi_ = 0; mi_ < 2; ++mi_) {                                              \
    _Pragma("unroll")                                                              \
    for (int kk_ = 0; kk_ < 2; ++kk_) {                                            \
      const int rl_ = wm2 + mi_ * 16 + lr;                                         \
      av[mi_][kk_] = *(const bf16x8*)&(REGION)[rl_ * 64 +                          \
          (((kk_ * 4 + lk) ^ (rl_ & 7)) << 3)];                                    \
    }                                                                              \
  }

#define READ_B(REGION, BV)                                                         \
  _Pragma("unroll")                                                                \
  for (int nj_ = 0; nj_ < 2; ++nj_) {                                              \
    _Pragma("unroll")                                                              \
    for (int kk_ = 0; kk_ < 2; ++kk_) {                                            \
      const int rl_ = wn2 + nj_ * 16 + lr;                                         \
      BV[nj_][kk_] = *(const bf16x8*)&(REGION)[rl_ * 64 +                          \
          (((kk_ * 4 + lk) ^ (rl_ & 7)) << 3)];                                    \
    }                                                                              \
  }

// 8 MFMA per phase
#define MMA(MH, NH, BV)                                                            \
  do {                                                                             \
    __builtin_amdgcn_s_setprio(1);                                                 \
    _Pragma("unroll")                                                              \
    for (int mi_ = 0; mi_ < 2; ++mi_)                                              \
      _Pragma("unroll")                                                            \
      for (int nj_ = 0; nj_ < 2; ++nj_)                                            \
        _Pragma("unroll")                                                          \
        for (int kk_ = 0; kk_ < 2; ++kk_)                                          \
          acc[(MH) * 2 + mi_][(NH) * 2 + nj_] =                                    \
              __builtin_amdgcn_mfma_f32_16x16x32_bf16(                             \
                  av[mi_][kk_], BV[nj_][kk_],                                      \
                  acc[(MH) * 2 + mi_][(NH) * 2 + nj_], 0, 0, 0);                   \
    __builtin_amdgcn_s_setprio(0);                                                 \
  } while (0)

// Tile τ (parity CB, NB). Quadrants Q00,Q01,Q11,Q10 (bv0 persists).
// Stage stream: P0:A1(τ+1) P1:B0(τ+2) P2:A0(τ+2) P3:B1(τ+2). Single vmcnt(6)
// at P3 retains the 3 newest halves => ALL of tile τ+1 guaranteed.
#define KTILE(CB, NB, T)                                                           \
  do {                                                                             \
    const int k1_ = ((T) + 1 < NT) ? ((T) + 1) * BK : 0;                           \
    const int k2_ = ((T) + 2 < NT) ? ((T) + 2) * BK : 0;                           \
    READ_A(AH(0, CB));                                                             \
    READ_B(BH(0, CB), bv0);                                                        \
    STAGE_H(Ag, 1, k1_, AH(1, NB));                                                \
    BAR(); MMA(0, 0, bv0); BAR();                                                  \
    READ_B(BH(1, CB), bv1);                                                        \
    STAGE_H(Bg, 0, k2_, BH(0, CB));                                                \
    BAR(); MMA(0, 1, bv1); BAR();                                                  \
    READ_A(AH(1, CB));                                                             \
    STAGE_H(Ag, 0, k2_, AH(0, CB));                                                \
    BAR(); MMA(1, 1, bv1); BAR();                                                  \
    STAGE_H(Bg, 1, k2_, BH(1, CB));                                                \
    WAITV6(); BAR(); MMA(1, 0, bv0); BAR();                                        \
  } while (0)

__global__ __launch_bounds__(256, 2) void lstm_gemm(
    const u16* __restrict__ Xc, const u16* __restrict__ Wc,
    const float* __restrict__ bc, const float* __restrict__ c0,
    float* __restrict__ out) {
  __shared__ __align__(16) char lds_raw[65536];

  const int tid = threadIdx.x;
  const int wave = tid >> 6, lane = tid & 63;
  const int lr = lane & 15, lk = lane >> 4;

  // bijective XCD swizzle: 2048 blocks, 256 consecutive tiles per XCD
  const int flat = blockIdx.y * gridDim.x + blockIdx.x;
  const int swz = (flat & 7) * 256 + (flat >> 3);
  const int bm = swz >> 5, bn = swz & 31;
  const int m0 = bm * BM, n0 = bn * BN;

  const int wm2 = (wave >> 1) * 32;   // 32-row band within each 64-row half
  const int wn2 = (wave & 1) * 32;    // 32-col band within each 64-col half

  f32x4 acc[4][4] = {};               // [mh*2+mi][nh*2+nj]
  bf16x8 av[2][2], bv0[2][2], bv1[2][2];

  const u16* Ag = Xc + (size_t)m0 * K_;
  const u16* Bg = Wc + (size_t)n0 * K_;

  // prologue: tile0 (4 halves) + tile1's B0,A0,B1; vmcnt(6) retires tile0 fully.
  STAGE_H(Ag, 0, 0, AH(0, 0));
  STAGE_H(Bg, 0, 0, BH(0, 0));
  STAGE_H(Bg, 1, 0, BH(1, 0));
  STAGE_H(Ag, 1, 0, AH(1, 0));
  STAGE_H(Bg, 0, BK, BH(0, 1));
  STAGE_H(Ag, 0, BK, AH(0, 1));
  STAGE_H(Bg, 1, BK, BH(1, 1));
  WAITV6();
  BAR();

#pragma unroll 1
  for (int tt = 0; tt < NT; tt += 2) {
    KTILE(0, 1, tt);
    KTILE(1, 0, tt + 1);
  }

  // ---- fused epilogue: 2 halves of 64 rows x 128 gate-cols via LDS transpose
  WAITV0();           // drain dummy tail stages before LDS reuse
  float* lE = (float*)lds_raw;        // [64][128] f32 = 32 KB
  float biasv[4];
#pragma unroll
  for (int an = 0; an < 4; ++an)
    biasv[an] = bc[n0 + (an >> 1) * 64 + wn2 + (an & 1) * 16 + lr];

#pragma unroll
  for (int half = 0; half < 2; ++half) {
    BARL();
#pragma unroll
    for (int mi = 0; mi < 2; ++mi)
#pragma unroll
      for (int an = 0; an < 4; ++an)
#pragma unroll
        for (int j = 0; j < 4; ++j)
          lE[(wm2 + mi * 16 + lk * 4 + j) * 128 +
             (an >> 1) * 64 + wn2 + (an & 1) * 16 + lr] =
              acc[half * 2 + mi][an][j] + biasv[an];
    BARL();
#pragma unroll
    for (int jj = 0; jj < 8; ++jj) {
      int item = jj * 256 + tid;
      int hl = item & 31, r = item >> 5;
      f32x4 pre = *(const f32x4*)&lE[r * 128 + hl * 4];
      int grow = m0 + half * 64 + r;
      int hg = (n0 >> 2) + hl;
      float c0v = c0[(size_t)grow * H_ + hg];
      float ig = sigmoidf_(pre[0]);
      float fg = sigmoidf_(pre[1]);
      float gg = tanhf_(pre[2]);
      float og = sigmoidf_(pre[3]);
      float ct = fg * c0v + ig * gg;
      float ht = og * tanhf_(ct);
      out[(size_t)grow * H_ + hg] = ht;
      out[(size_t)(B_ * H_) + (size_t)grow * H_ + hg] = ct;
    }
  }
}

extern "C" void kernel_launch(void* const* d_in, const int* in_sizes, int n_in,
                              void* d_out, int out_size, void* d_ws, size_t ws_size,
                              hipStream_t stream) {
  const float* x   = (const float*)d_in[0];
  const float* h0  = (const float*)d_in[1];
  const float* c0  = (const float*)d_in[2];
  const float* W_i = (const float*)d_in[3];
  const float* W_h = (const float*)d_in[4];
  const float* b_i = (const float*)d_in[5];
  const float* b_h = (const float*)d_in[6];
  const float* A_i = (const float*)d_in[7];
  const float* B_i = (const float*)d_in[8];
  const float* A_h = (const float*)d_in[9];
  const float* B_h = (const float*)d_in[10];
  float* out = (float*)d_out;

  char* ws = (char*)d_ws;
  u16*   Xc = (u16*)ws;                                   // 32 MB
  u16*   Wc = (u16*)(ws + ((size_t)32 << 20));            // 16 MB
  float* bc = (float*)(ws + ((size_t)48 << 20));          // 16 KB

  prep_x<<<dim3(B_ * K_ / 8 / 256), dim3(256), 0, stream>>>(x, h0, Xc);
  prep_w<<<dim3(4 * H_), dim3(256), 0, stream>>>(W_i, W_h, b_i, b_h,
                                                 A_i, B_i, A_h, B_h, Wc, bc);
  lstm_gemm<<<dim3(N_ / BN, B_ / BM), dim3(256), 0, stream>>>(Xc, Wc, bc, c0, out);
}

// Round 8
// 170.215 us; speedup vs baseline: 1.5581x; 1.5581x over previous
//
#include <hip/hip_runtime.h>
#include <hip/hip_bf16.h>
#include <cstdint>

#define B_  8192
#define I_  1024
#define H_  1024
#define R_  16
#define K_  2048   // I_ + H_
#define N_  4096   // 4 * H_

typedef __attribute__((ext_vector_type(4))) float f32x4;
typedef __attribute__((ext_vector_type(8))) __bf16 bf16x8;
typedef __attribute__((ext_vector_type(8))) unsigned short u16x8;
typedef __attribute__((ext_vector_type(4))) unsigned short u16x4;
typedef unsigned short u16;

__device__ __forceinline__ u16 f2bf(float f) {
  union { float f; unsigned u; } v; v.f = f;
  unsigned u = v.u;
  return (u16)((u + 0x7fffu + ((u >> 16) & 1u)) >> 16);  // RNE
}

__device__ __forceinline__ float sigmoidf_(float x) {
  return 1.0f / (1.0f + __expf(-x));
}
__device__ __forceinline__ float tanhf_(float x) {
  return 1.0f - 2.0f / (__expf(2.0f * x) + 1.0f);  // inf-safe both tails
}

// ---- fused prep: blocks [0,8192) pack [x|h0]->bf16 Xc; [8192,12288) fold LoRA ----
__global__ __launch_bounds__(256) void prep_all(
    const float* __restrict__ x, const float* __restrict__ h0,
    const float* __restrict__ W_i, const float* __restrict__ W_h,
    const float* __restrict__ b_i, const float* __restrict__ b_h,
    const float* __restrict__ A_i, const float* __restrict__ Bi,
    const float* __restrict__ A_h, const float* __restrict__ Bh,
    u16* __restrict__ Xc, u16* __restrict__ Wc, float* __restrict__ bc) {
  const int bid = blockIdx.x;
  const int tid = threadIdx.x;
  if (bid < 8192) {
    // ---- pack [x | h0] -> bf16 Xc[B][K], 8 elems/thread ----
    int idx = bid * 256 + tid;
    int e = idx << 3;
    int b = e >> 11;
    int k = e & (K_ - 1);
    const float* src = (k < I_) ? (x + ((size_t)b << 10) + k)
                                : (h0 + ((size_t)b << 10) + (k - I_));
    const f32x4 v0 = *(const f32x4*)src;
    const f32x4 v1 = *(const f32x4*)(src + 4);
    u16x8 o;
    o[0] = f2bf(v0[0]); o[1] = f2bf(v0[1]); o[2] = f2bf(v0[2]); o[3] = f2bf(v0[3]);
    o[4] = f2bf(v1[0]); o[5] = f2bf(v1[1]); o[6] = f2bf(v1[2]); o[7] = f2bf(v1[3]);
    *(u16x8*)(Xc + (size_t)e) = o;
  } else {
    // ---- fold LoRA into weights, bf16, gate-interleaved rows n=h*4+g ----
    const int gh = bid - 8192;          // (g,h)
    const int g = gh >> 10, h = gh & (H_ - 1);
    float bi[R_], bh[R_];
#pragma unroll
    for (int r = 0; r < R_; ++r) {
      bi[r] = Bi[((size_t)(g * H_ + h) << 4) + r];
      bh[r] = Bh[((size_t)(g * H_ + h) << 4) + r];
    }
    u16* dst = Wc + (size_t)(h * 4 + g) * K_;
    const float* wi = W_i + ((size_t)(g * H_ + h) << 10);
    const float* wh = W_h + ((size_t)(g * H_ + h) << 10);
    const int k4 = tid * 4;             // 256 thr x 4 = 1024 k
    f32x4 accI = *(const f32x4*)&wi[k4];
    f32x4 accH = *(const f32x4*)&wh[k4];
#pragma unroll
    for (int r = 0; r < R_; ++r) {
      const f32x4 ai = *(const f32x4*)&A_i[((size_t)(g * R_ + r) << 10) + k4];
      const f32x4 ah = *(const f32x4*)&A_h[((size_t)(g * R_ + r) << 10) + k4];
      accI += bi[r] * ai;
      accH += bh[r] * ah;
    }
    u16x4 oi, oh;
#pragma unroll
    for (int j = 0; j < 4; ++j) { oi[j] = f2bf(accI[j]); oh[j] = f2bf(accH[j]); }
    *(u16x4*)(dst + k4) = oi;
    *(u16x4*)(dst + I_ + k4) = oh;
    if (tid == 0) bc[h * 4 + g] = b_i[g * H_ + h] + b_h[g * H_ + h];
  }
}

// ------- 256x256 GEMM, per-half-slot dbuf + single vmcnt(6)/K-tile + fused LSTM -------
#define BM 256
#define BN 256
#define BK 64
#define NT (K_ / BK)   // 32 K-tiles

#define GLOAD_LDS16(gp, lp)                                                        \
  __builtin_amdgcn_global_load_lds(                                                \
      (const __attribute__((address_space(1))) void*)(gp),                         \
      (__attribute__((address_space(3))) void*)(lp), 16, 0, 0)

#define BAR()                                                                      \
  do { asm volatile("" ::: "memory"); __builtin_amdgcn_s_barrier();                \
       asm volatile("" ::: "memory"); } while (0)

#define BARL()                                                                     \
  do { asm volatile("s_waitcnt lgkmcnt(0)" ::: "memory");                          \
       __builtin_amdgcn_s_barrier(); asm volatile("" ::: "memory"); } while (0)

#define WAITV0() asm volatile("s_waitcnt vmcnt(0)" ::: "memory")
#define WAITV6() asm volatile("s_waitcnt vmcnt(6)" ::: "memory")

// 16 KB half-tile regions: A halves at 0..64KB, B halves at 64..128KB.
#define AH(HI, SL) ((u16*)(lds_raw + ((HI) * 2 + (SL)) * 16384))
#define BH(HI, SL) ((u16*)(lds_raw + 65536 + ((HI) * 2 + (SL)) * 16384))

// stage one half-tile (128 rows x 64 cols bf16 = 16KB): 2x16B/thread.
// LDS dest linear; T2 swizzle via XOR-permuted global source chunk (rule #21).
#define STAGE_H(GBASE, HALF, K0N, REGION)                                          \
  _Pragma("unroll")                                                                \
  for (int r_ = 0; r_ < 2; ++r_) {                                                 \
    int chunk_ = r_ * 512 + tid;                                                   \
    int rl_ = chunk_ >> 3, cp_ = chunk_ & 7;                                       \
    int cc_ = cp_ ^ (rl_ & 7);                                                     \
    GLOAD_LDS16((GBASE) + (size_t)((HALF) * 128 + rl_) * K_ + (K0N) + cc_ * 8,     \
                (char*)(REGION) + chunk_ * 16);                                    \
  }

#define READ_A(REGION)                                                             \
  _Pragma("unroll")                                                                \
  for (int mi_ = 0; mi_ < 4; ++mi_) {                                              \
    _Pragma("unroll")                                                              \
    for (int kk_ = 0; kk_ < 2; ++kk_) {                                            \
      const int rl_ = wave_m + mi_ * 16 + lr;                                      \
      av[mi_][kk_] = *(const bf16x8*)&(REGION)[rl_ * 64 +                          \
          (((kk_ * 4 + lk) ^ (rl_ & 7)) << 3)];                                    \
    }                                                                              \
  }

#define READ_B(REGION, BV)                                                         \
  _Pragma("unroll")                                                                \
  for (int nj_ = 0; nj_ < 2; ++nj_) {                                              \
    _Pragma("unroll")                                                              \
    for (int kk_ = 0; kk_ < 2; ++kk_) {                                            \
      const int rl_ = wave_n + nj_ * 16 + lr;                                      \
      BV[nj_][kk_] = *(const bf16x8*)&(REGION)[rl_ * 64 +                          \
          (((kk_ * 4 + lk) ^ (rl_ & 7)) << 3)];                                    \
    }                                                                              \
  }

#define MMA(MH, NH, BV)                                                            \
  do {                                                                             \
    __builtin_amdgcn_s_setprio(1);                                                 \
    _Pragma("unroll")                                                              \
    for (int mi_ = 0; mi_ < 4; ++mi_)                                              \
      _Pragma("unroll")                                                            \
      for (int nj_ = 0; nj_ < 2; ++nj_)                                            \
        _Pragma("unroll")                                                          \
        for (int kk_ = 0; kk_ < 2; ++kk_)                                          \
          acc[(MH) * 4 + mi_][(NH) * 2 + nj_] =                                    \
              __builtin_amdgcn_mfma_f32_16x16x32_bf16(                             \
                  av[mi_][kk_], BV[nj_][kk_],                                      \
                  acc[(MH) * 4 + mi_][(NH) * 2 + nj_], 0, 0, 0);                   \
    __builtin_amdgcn_s_setprio(0);                                                 \
  } while (0)

// Tile τ (parity CB, NB). Quadrants Q00,Q01,Q11,Q10 (bv0 persists).
// Stage stream: P0:A1(τ+1) P1:B0(τ+2) P2:A0(τ+2) P3:B1(τ+2). Single vmcnt(6)
// at P3 retains the 3 newest halves => ALL of tile τ+1 guaranteed.
#define KTILE(CB, NB, T)                                                           \
  do {                                                                             \
    const int k1_ = ((T) + 1 < NT) ? ((T) + 1) * BK : 0;                           \
    const int k2_ = ((T) + 2 < NT) ? ((T) + 2) * BK : 0;                           \
    READ_A(AH(0, CB));                                                             \
    READ_B(BH(0, CB), bv0);                                                        \
    STAGE_H(Ag, 1, k1_, AH(1, NB));                                                \
    BAR(); MMA(0, 0, bv0); BAR();                                                  \
    READ_B(BH(1, CB), bv1);                                                        \
    STAGE_H(Bg, 0, k2_, BH(0, CB));                                                \
    BAR(); MMA(0, 1, bv1); BAR();                                                  \
    READ_A(AH(1, CB));                                                             \
    STAGE_H(Ag, 0, k2_, AH(0, CB));                                                \
    BAR(); MMA(1, 1, bv1); BAR();                                                  \
    STAGE_H(Bg, 1, k2_, BH(1, CB));                                                \
    WAITV6(); BAR(); MMA(1, 0, bv0); BAR();                                        \
  } while (0)

__global__ __launch_bounds__(512, 2) void lstm_gemm(
    const u16* __restrict__ Xc, const u16* __restrict__ Wc,
    const float* __restrict__ bc, const float* __restrict__ c0,
    float* __restrict__ out) {
  __shared__ __align__(16) char lds_raw[131072];

  const int tid = threadIdx.x;
  const int wave = tid >> 6, lane = tid & 63;
  const int lr = lane & 15, lk = lane >> 4;

  // bijective XCD swizzle: 512 blocks, 64 consecutive tiles per XCD
  const int flat = blockIdx.y * gridDim.x + blockIdx.x;
  const int swz = (flat & 7) * 64 + (flat >> 3);
  const int bm = swz >> 4, bn = swz & 15;
  const int m0 = bm * BM, n0 = bn * BN;

  const int wave_m = (wave >> 2) * 64;   // M sub-block within each 128-row M-half
  const int wave_n = (wave & 3) * 32;    // N sub-block within each 128-col N-half

  f32x4 acc[8][4] = {};
  bf16x8 av[4][2], bv0[2][2], bv1[2][2];

  const u16* Ag = Xc + (size_t)m0 * K_;
  const u16* Bg = Wc + (size_t)n0 * K_;

  // prologue: tile0 (4 halves) + tile1's B0,A0,B1; vmcnt(6) retires tile0 fully.
  STAGE_H(Ag, 0, 0, AH(0, 0));
  STAGE_H(Bg, 0, 0, BH(0, 0));
  STAGE_H(Bg, 1, 0, BH(1, 0));
  STAGE_H(Ag, 1, 0, AH(1, 0));
  STAGE_H(Bg, 0, BK, BH(0, 1));
  STAGE_H(Ag, 0, BK, AH(0, 1));
  STAGE_H(Bg, 1, BK, BH(1, 1));
  WAITV6();
  BAR();

#pragma unroll 1
  for (int tt = 0; tt < NT; tt += 2) {
    KTILE(0, 1, tt);
    KTILE(1, 0, tt + 1);
  }

  // ---- fused epilogue: 2 halves of 128 rows x 256 gate-cols via LDS transpose.
  // lE col bits 4-5 XOR'd with (row&3)^((row>>2)&3): kills both the writer's
  // 4-way (lk axis) and reader's 4-way (row axis, 1024B bank-aligned stride).
  WAITV0();           // drain dummy tail stages before LDS reuse
  float* lE = (float*)lds_raw;        // [128][256] f32 = 128 KB
  float biasv[4];
#pragma unroll
  for (int an = 0; an < 4; ++an)
    biasv[an] = bc[n0 + (an >> 1) * 128 + wave_n + (an & 1) * 16 + lr];

#pragma unroll
  for (int half = 0; half < 2; ++half) {
    BARL();
#pragma unroll
    for (int mi = 0; mi < 4; ++mi)
#pragma unroll
      for (int an = 0; an < 4; ++an)
#pragma unroll
        for (int j = 0; j < 4; ++j) {
          const int row = wave_m + mi * 16 + lk * 4 + j;
          const int col = (an >> 1) * 128 + wave_n + (an & 1) * 16 + lr;
          const int colx = col ^ ((((row & 3) ^ ((row >> 2) & 3))) << 4);
          lE[row * 256 + colx] = acc[half * 4 + mi][an][j] + biasv[an];
        }
    BARL();
#pragma unroll
    for (int jj = 0; jj < 4; ++jj) {
      const int item = jj * 512 + tid;
      const int hl4 = item & 15;        // 16 groups of 4 h-units
      const int rr = item >> 4;         // 0..127
      const int xorv = ((rr & 3) ^ ((rr >> 2) & 3)) << 4;
      const int grow = m0 + half * 128 + rr;
      const int hg = (n0 >> 2) + hl4 * 4;
      const f32x4 c0v = *(const f32x4*)&c0[(size_t)grow * H_ + hg];
      f32x4 htv, ctv;
#pragma unroll
      for (int q = 0; q < 4; ++q) {
        const int colx = (hl4 * 16 + q * 4) ^ xorv;
        const f32x4 pre = *(const f32x4*)&lE[rr * 256 + colx];
        float ig = sigmoidf_(pre[0]);
        float fg = sigmoidf_(pre[1]);
        float gg = tanhf_(pre[2]);
        float og = sigmoidf_(pre[3]);
        float ct = fg * c0v[q] + ig * gg;
        htv[q] = og * tanhf_(ct);
        ctv[q] = ct;
      }
      *(f32x4*)&out[(size_t)grow * H_ + hg] = htv;
      *(f32x4*)&out[(size_t)(B_ * H_) + (size_t)grow * H_ + hg] = ctv;
    }
  }
}

extern "C" void kernel_launch(void* const* d_in, const int* in_sizes, int n_in,
                              void* d_out, int out_size, void* d_ws, size_t ws_size,
                              hipStream_t stream) {
  const float* x   = (const float*)d_in[0];
  const float* h0  = (const float*)d_in[1];
  const float* c0  = (const float*)d_in[2];
  const float* W_i = (const float*)d_in[3];
  const float* W_h = (const float*)d_in[4];
  const float* b_i = (const float*)d_in[5];
  const float* b_h = (const float*)d_in[6];
  const float* A_i = (const float*)d_in[7];
  const float* B_i = (const float*)d_in[8];
  const float* A_h = (const float*)d_in[9];
  const float* B_h = (const float*)d_in[10];
  float* out = (float*)d_out;

  char* ws = (char*)d_ws;
  u16*   Xc = (u16*)ws;                                   // 32 MB
  u16*   Wc = (u16*)(ws + ((size_t)32 << 20));            // 16 MB
  float* bc = (float*)(ws + ((size_t)48 << 20));          // 16 KB

  prep_all<<<dim3(8192 + 4096), dim3(256), 0, stream>>>(
      x, h0, W_i, W_h, b_i, b_h, A_i, B_i, A_h, B_h, Xc, Wc, bc);
  lstm_gemm<<<dim3(N_ / BN, B_ / BM), dim3(512), 0, stream>>>(Xc, Wc, bc, c0, out);
}

// Round 9
// 167.326 us; speedup vs baseline: 1.5850x; 1.0173x over previous
//
#include <hip/hip_runtime.h>
#include <hip/hip_bf16.h>
#include <cstdint>

#define B_  8192
#define I_  1024
#define H_  1024
#define R_  16
#define K_  2048   // I_ + H_
#define N_  4096   // 4 * H_

typedef __attribute__((ext_vector_type(4))) float f32x4;
typedef __attribute__((ext_vector_type(8))) __bf16 bf16x8;
typedef __attribute__((ext_vector_type(8))) unsigned short u16x8;
typedef __attribute__((ext_vector_type(4))) unsigned short u16x4;
typedef unsigned short u16;

__device__ __forceinline__ u16 f2bf(float f) {
  union { float f; unsigned u; } v; v.f = f;
  unsigned u = v.u;
  return (u16)((u + 0x7fffu + ((u >> 16) & 1u)) >> 16);  // RNE
}

__device__ __forceinline__ float sigmoidf_(float x) {
  return 1.0f / (1.0f + __expf(-x));
}
__device__ __forceinline__ float tanhf_(float x) {
  return 1.0f - 2.0f / (__expf(2.0f * x) + 1.0f);  // inf-safe both tails
}

// ---- fused prep: blocks [0,8192) pack [x|h0]->bf16 Xc; [8192,12288) fold LoRA ----
__global__ __launch_bounds__(256) void prep_all(
    const float* __restrict__ x, const float* __restrict__ h0,
    const float* __restrict__ W_i, const float* __restrict__ W_h,
    const float* __restrict__ b_i, const float* __restrict__ b_h,
    const float* __restrict__ A_i, const float* __restrict__ Bi,
    const float* __restrict__ A_h, const float* __restrict__ Bh,
    u16* __restrict__ Xc, u16* __restrict__ Wc, float* __restrict__ bc) {
  const int bid = blockIdx.x;
  const int tid = threadIdx.x;
  if (bid < 8192) {
    int idx = bid * 256 + tid;
    int e = idx << 3;
    int b = e >> 11;
    int k = e & (K_ - 1);
    const float* src = (k < I_) ? (x + ((size_t)b << 10) + k)
                                : (h0 + ((size_t)b << 10) + (k - I_));
    const f32x4 v0 = *(const f32x4*)src;
    const f32x4 v1 = *(const f32x4*)(src + 4);
    u16x8 o;
    o[0] = f2bf(v0[0]); o[1] = f2bf(v0[1]); o[2] = f2bf(v0[2]); o[3] = f2bf(v0[3]);
    o[4] = f2bf(v1[0]); o[5] = f2bf(v1[1]); o[6] = f2bf(v1[2]); o[7] = f2bf(v1[3]);
    *(u16x8*)(Xc + (size_t)e) = o;
  } else {
    const int gh = bid - 8192;          // (g,h)
    const int g = gh >> 10, h = gh & (H_ - 1);
    float bi[R_], bh[R_];
#pragma unroll
    for (int r = 0; r < R_; ++r) {
      bi[r] = Bi[((size_t)(g * H_ + h) << 4) + r];
      bh[r] = Bh[((size_t)(g * H_ + h) << 4) + r];
    }
    u16* dst = Wc + (size_t)(h * 4 + g) * K_;
    const float* wi = W_i + ((size_t)(g * H_ + h) << 10);
    const float* wh = W_h + ((size_t)(g * H_ + h) << 10);
    const int k4 = tid * 4;             // 256 thr x 4 = 1024 k
    f32x4 accI = *(const f32x4*)&wi[k4];
    f32x4 accH = *(const f32x4*)&wh[k4];
#pragma unroll
    for (int r = 0; r < R_; ++r) {
      const f32x4 ai = *(const f32x4*)&A_i[((size_t)(g * R_ + r) << 10) + k4];
      const f32x4 ah = *(const f32x4*)&A_h[((size_t)(g * R_ + r) << 10) + k4];
      accI += bi[r] * ai;
      accH += bh[r] * ah;
    }
    u16x4 oi, oh;
#pragma unroll
    for (int j = 0; j < 4; ++j) { oi[j] = f2bf(accI[j]); oh[j] = f2bf(accH[j]); }
    *(u16x4*)(dst + k4) = oi;
    *(u16x4*)(dst + I_ + k4) = oh;
    if (tid == 0) bc[h * 4 + g] = b_i[g * H_ + h] + b_h[g * H_ + h];
  }
}

// -- 256x256 GEMM, 1-barrier phases, stage-post-bar, vmcnt(4)/K-tile + fused LSTM --
#define BM 256
#define BN 256
#define BK 64
#define NT (K_ / BK)   // 32 K-tiles

#define GLOAD_LDS16(gp, lp)                                                        \
  __builtin_amdgcn_global_load_lds(                                                \
      (const __attribute__((address_space(1))) void*)(gp),                         \
      (__attribute__((address_space(3))) void*)(lp), 16, 0, 0)

#define BAR()                                                                      \
  do { asm volatile("" ::: "memory"); __builtin_amdgcn_s_barrier();                \
       asm volatile("" ::: "memory"); } while (0)

#define BARL()                                                                     \
  do { asm volatile("s_waitcnt lgkmcnt(0)" ::: "memory");                          \
       __builtin_amdgcn_s_barrier(); asm volatile("" ::: "memory"); } while (0)

#define WAITV0() asm volatile("s_waitcnt vmcnt(0)" ::: "memory")
#define WAITV4() asm volatile("s_waitcnt vmcnt(4)" ::: "memory")

// 16 KB half-tile regions: A halves at 0..64KB, B halves at 64..128KB.
#define AH(HI, SL) ((u16*)(lds_raw + ((HI) * 2 + (SL)) * 16384))
#define BH(HI, SL) ((u16*)(lds_raw + 65536 + ((HI) * 2 + (SL)) * 16384))

// stage one half-tile (128 rows x 64 cols bf16 = 16KB): 2x16B/thread.
// LDS dest linear; T2 swizzle via XOR-permuted global source chunk (rule #21).
#define STAGE_H(GBASE, HALF, K0N, REGION)                                          \
  _Pragma("unroll")                                                                \
  for (int r_ = 0; r_ < 2; ++r_) {                                                 \
    int chunk_ = r_ * 512 + tid;                                                   \
    int rl_ = chunk_ >> 3, cp_ = chunk_ & 7;                                       \
    int cc_ = cp_ ^ (rl_ & 7);                                                     \
    GLOAD_LDS16((GBASE) + (size_t)((HALF) * 128 + rl_) * K_ + (K0N) + cc_ * 8,     \
                (char*)(REGION) + chunk_ * 16);                                    \
  }

#define READ_A(REGION)                                                             \
  _Pragma("unroll")                                                                \
  for (int mi_ = 0; mi_ < 4; ++mi_) {                                              \
    _Pragma("unroll")                                                              \
    for (int kk_ = 0; kk_ < 2; ++kk_) {                                            \
      const int rl_ = wave_m + mi_ * 16 + lr;                                      \
      av[mi_][kk_] = *(const bf16x8*)&(REGION)[rl_ * 64 +                          \
          (((kk_ * 4 + lk) ^ (rl_ & 7)) << 3)];                                    \
    }                                                                              \
  }

#define READ_B(REGION, BV)                                                         \
  _Pragma("unroll")                                                                \
  for (int nj_ = 0; nj_ < 2; ++nj_) {                                              \
    _Pragma("unroll")                                                              \
    for (int kk_ = 0; kk_ < 2; ++kk_) {                                            \
      const int rl_ = wave_n + nj_ * 16 + lr;                                      \
      BV[nj_][kk_] = *(const bf16x8*)&(REGION)[rl_ * 64 +                          \
          (((kk_ * 4 + lk) ^ (rl_ & 7)) << 3)];                                    \
    }                                                                              \
  }

#define MMA(MH, NH, BV)                                                            \
  do {                                                                             \
    __builtin_amdgcn_s_setprio(1);                                                 \
    _Pragma("unroll")                                                              \
    for (int mi_ = 0; mi_ < 4; ++mi_)                                              \
      _Pragma("unroll")                                                            \
      for (int nj_ = 0; nj_ < 2; ++nj_)                                            \
        _Pragma("unroll")                                                          \
        for (int kk_ = 0; kk_ < 2; ++kk_)                                          \
          acc[(MH) * 4 + mi_][(NH) * 2 + nj_] =                                    \
              __builtin_amdgcn_mfma_f32_16x16x32_bf16(                             \
                  av[mi_][kk_], BV[nj_][kk_],                                      \
                  acc[(MH) * 4 + mi_][(NH) * 2 + nj_], 0, 0, 0);                   \
    __builtin_amdgcn_s_setprio(0);                                                 \
  } while (0)

// Tile τ (parity CB, NB). ONE barrier per phase; stages placed AFTER the
// barrier so a region's pending reads (consumed by the MFMA preceding that
// barrier) are complete before the write can land. Quadrants Q00,Q01,Q11,Q10.
// Stage stream: P0:A1(τ+1) P1:B0(τ+2) P2:A0(τ+2) P3:B1(τ+2).
// vmcnt(4) at P3 retires ALL four halves of tile τ+1 (ledger: 6 in flight
// entering τ, +6 at P0-P2, retire 8 = τ-1's P1-P3 stages + τ's P0 stage).
#define KTILE(CB, NB, T)                                                           \
  do {                                                                             \
    const int k1_ = ((T) + 1 < NT) ? ((T) + 1) * BK : 0;                           \
    const int k2_ = ((T) + 2 < NT) ? ((T) + 2) * BK : 0;                           \
    READ_A(AH(0, CB));                                                             \
    READ_B(BH(0, CB), bv0);                                                        \
    BAR();                                                                         \
    STAGE_H(Ag, 1, k1_, AH(1, NB));                                                \
    MMA(0, 0, bv0);                                                                \
    READ_B(BH(1, CB), bv1);                                                        \
    BAR();                                                                         \
    STAGE_H(Bg, 0, k2_, BH(0, CB));                                                \
    MMA(0, 1, bv1);                                                                \
    READ_A(AH(1, CB));                                                             \
    BAR();                                                                         \
    STAGE_H(Ag, 0, k2_, AH(0, CB));                                                \
    MMA(1, 1, bv1);                                                                \
    WAITV4();                                                                      \
    BAR();                                                                         \
    STAGE_H(Bg, 1, k2_, BH(1, CB));                                                \
    MMA(1, 0, bv0);                                                                \
  } while (0)

__global__ __launch_bounds__(512, 2) void lstm_gemm(
    const u16* __restrict__ Xc, const u16* __restrict__ Wc,
    const float* __restrict__ bc, const float* __restrict__ c0,
    float* __restrict__ out) {
  __shared__ __align__(16) char lds_raw[131072];

  const int tid = threadIdx.x;
  const int wave = tid >> 6, lane = tid & 63;
  const int lr = lane & 15, lk = lane >> 4;

  // bijective XCD swizzle: 512 blocks, 64 consecutive tiles per XCD
  const int flat = blockIdx.y * gridDim.x + blockIdx.x;
  const int swz = (flat & 7) * 64 + (flat >> 3);
  const int bm = swz >> 4, bn = swz & 15;
  const int m0 = bm * BM, n0 = bn * BN;

  const int wave_m = (wave >> 2) * 64;   // M sub-block within each 128-row M-half
  const int wave_n = (wave & 3) * 32;    // N sub-block within each 128-col N-half

  f32x4 acc[8][4] = {};
  bf16x8 av[4][2], bv0[2][2], bv1[2][2];

  const u16* Ag = Xc + (size_t)m0 * K_;
  const u16* Bg = Wc + (size_t)n0 * K_;

  // prologue: tile0 (4 halves) + tile1's B0,A0; vmcnt(4) retires tile0 fully;
  // then stage B1(1) so steady-state entering outstanding = 6 loads.
  STAGE_H(Ag, 0, 0, AH(0, 0));
  STAGE_H(Bg, 0, 0, BH(0, 0));
  STAGE_H(Bg, 1, 0, BH(1, 0));
  STAGE_H(Ag, 1, 0, AH(1, 0));
  STAGE_H(Bg, 0, BK, BH(0, 1));
  STAGE_H(Ag, 0, BK, AH(0, 1));
  WAITV4();
  BAR();
  STAGE_H(Bg, 1, BK, BH(1, 1));

#pragma unroll 1
  for (int tt = 0; tt < NT; tt += 2) {
    KTILE(0, 1, tt);
    KTILE(1, 0, tt + 1);
  }

  // ---- fused epilogue: 2 halves of 128 rows x 256 gate-cols via LDS transpose.
  // lE col bits 4-5 XOR'd with (row&3)^((row>>2)&3): kills both the writer's
  // 4-way (lk axis) and reader's 4-way (row axis, 1024B bank-aligned stride).
  WAITV0();           // drain dummy tail stages before LDS reuse
  float* lE = (float*)lds_raw;        // [128][256] f32 = 128 KB
  float biasv[4];
#pragma unroll
  for (int an = 0; an < 4; ++an)
    biasv[an] = bc[n0 + (an >> 1) * 128 + wave_n + (an & 1) * 16 + lr];

#pragma unroll
  for (int half = 0; half < 2; ++half) {
    BARL();
#pragma unroll
    for (int mi = 0; mi < 4; ++mi)
#pragma unroll
      for (int an = 0; an < 4; ++an)
#pragma unroll
        for (int j = 0; j < 4; ++j) {
          const int row = wave_m + mi * 16 + lk * 4 + j;
          const int col = (an >> 1) * 128 + wave_n + (an & 1) * 16 + lr;
          const int colx = col ^ ((((row & 3) ^ ((row >> 2) & 3))) << 4);
          lE[row * 256 + colx] = acc[half * 4 + mi][an][j] + biasv[an];
        }
    BARL();
#pragma unroll
    for (int jj = 0; jj < 4; ++jj) {
      const int item = jj * 512 + tid;
      const int hl4 = item & 15;        // 16 groups of 4 h-units
      const int rr = item >> 4;         // 0..127
      const int xorv = ((rr & 3) ^ ((rr >> 2) & 3)) << 4;
      const int grow = m0 + half * 128 + rr;
      const int hg = (n0 >> 2) + hl4 * 4;
      const f32x4 c0v = *(const f32x4*)&c0[(size_t)grow * H_ + hg];
      f32x4 htv, ctv;
#pragma unroll
      for (int q = 0; q < 4; ++q) {
        const int colx = (hl4 * 16 + q * 4) ^ xorv;
        const f32x4 pre = *(const f32x4*)&lE[rr * 256 + colx];
        float ig = sigmoidf_(pre[0]);
        float fg = sigmoidf_(pre[1]);
        float gg = tanhf_(pre[2]);
        float og = sigmoidf_(pre[3]);
        float ct = fg * c0v[q] + ig * gg;
        htv[q] = og * tanhf_(ct);
        ctv[q] = ct;
      }
      *(f32x4*)&out[(size_t)grow * H_ + hg] = htv;
      *(f32x4*)&out[(size_t)(B_ * H_) + (size_t)grow * H_ + hg] = ctv;
    }
  }
}

extern "C" void kernel_launch(void* const* d_in, const int* in_sizes, int n_in,
                              void* d_out, int out_size, void* d_ws, size_t ws_size,
                              hipStream_t stream) {
  const float* x   = (const float*)d_in[0];
  const float* h0  = (const float*)d_in[1];
  const float* c0  = (const float*)d_in[2];
  const float* W_i = (const float*)d_in[3];
  const float* W_h = (const float*)d_in[4];
  const float* b_i = (const float*)d_in[5];
  const float* b_h = (const float*)d_in[6];
  const float* A_i = (const float*)d_in[7];
  const float* B_i = (const float*)d_in[8];
  const float* A_h = (const float*)d_in[9];
  const float* B_h = (const float*)d_in[10];
  float* out = (float*)d_out;

  char* ws = (char*)d_ws;
  u16*   Xc = (u16*)ws;                                   // 32 MB
  u16*   Wc = (u16*)(ws + ((size_t)32 << 20));            // 16 MB
  float* bc = (float*)(ws + ((size_t)48 << 20));          // 16 KB

  prep_all<<<dim3(8192 + 4096), dim3(256), 0, stream>>>(
      x, h0, W_i, W_h, b_i, b_h, A_i, B_i, A_h, B_h, Xc, Wc, bc);
  lstm_gemm<<<dim3(N_ / BN, B_ / BM), dim3(512), 0, stream>>>(Xc, Wc, bc, c0, out);
}